// Round 8
// baseline (1169.414 us; speedup 1.0000x reference)
//
#include <hip/hip_runtime.h>
#include <hip/hip_bf16.h>
#include <math.h>

#define NROW 1920      // B*T
#define VOCAB_ 50000
#define NPAD 50048     // 391 * 128
#define NBLK 391
#define CAP 128        // max argmax candidates per row

typedef __attribute__((ext_vector_type(8))) short short8;
typedef __attribute__((ext_vector_type(4))) float floatx4;

__device__ inline ushort f32_to_bf16_bits(float f) {
    union { float f; unsigned u; } v; v.f = f;
    unsigned u = v.u;
    u += 0x7fffu + ((u >> 16) & 1u);   // RNE
    return (ushort)(u >> 16);
}

// ---------------------------------------------------------------------------
// Front GEMM: gh (blocks 0..11) and gi (blocks 12..371) in one launch.
//   gh = h0 @ W_hh^T + b_hh            (64 x 768, K=256)
//   gi = wemb[tokens] @ W_ih^T + b_ih  (1920 x 768, K=256, gather fused)
// ---------------------------------------------------------------------------
__global__ __launch_bounds__(256) void front_gemm_kernel(
    const float* __restrict__ h0, const float* __restrict__ W_hh,
    const float* __restrict__ b_hh, float* __restrict__ gh,
    const int* __restrict__ tokens, const float* __restrict__ wemb,
    const float* __restrict__ W_ih, const float* __restrict__ b_ih,
    float* __restrict__ gi) {
    __shared__ float As[32][68];
    __shared__ float Bs[32][68];
    __shared__ int tok_s[64];

    const int tid = threadIdx.x;
    const int bid = blockIdx.x;
    const bool is_gh = (bid < 12);

    int m0, n0;
    const float* Bm;
    const float* bias;
    float* C;
    if (is_gh) {
        m0 = 0; n0 = bid * 64; Bm = W_hh; bias = b_hh; C = gh;
    } else {
        int bb = bid - 12;
        m0 = (bb / 12) * 64; n0 = (bb % 12) * 64;
        Bm = W_ih; bias = b_ih; C = gi;
    }

    if (!is_gh && tid < 64) tok_s[tid] = tokens[m0 + tid];
    __syncthreads();

    const int tx = tid & 15;
    const int ty = tid >> 4;
    const int lrow = tid >> 3;
    const int lcol = (tid & 7) * 4;

    float acc[4][4];
#pragma unroll
    for (int i = 0; i < 4; ++i)
#pragma unroll
        for (int j = 0; j < 4; ++j) acc[i][j] = 0.f;

    for (int k0 = 0; k0 < 256; k0 += 32) {
#pragma unroll
        for (int half = 0; half < 2; ++half) {
            int m = lrow + half * 32;
            const float* arow = is_gh ? (h0 + (size_t)(m0 + m) * 256)
                                      : (wemb + (size_t)tok_s[m] * 256);
            float4 av = *reinterpret_cast<const float4*>(arow + k0 + lcol);
            As[lcol + 0][m] = av.x; As[lcol + 1][m] = av.y;
            As[lcol + 2][m] = av.z; As[lcol + 3][m] = av.w;
            int n = lrow + half * 32;
            float4 bv = *reinterpret_cast<const float4*>(
                Bm + (size_t)(n0 + n) * 256 + k0 + lcol);
            Bs[lcol + 0][n] = bv.x; Bs[lcol + 1][n] = bv.y;
            Bs[lcol + 2][n] = bv.z; Bs[lcol + 3][n] = bv.w;
        }
        __syncthreads();
#pragma unroll
        for (int k = 0; k < 32; ++k) {
            float4 a4 = *reinterpret_cast<const float4*>(&As[k][ty * 4]);
            float4 b4 = *reinterpret_cast<const float4*>(&Bs[k][tx * 4]);
            float a[4] = {a4.x, a4.y, a4.z, a4.w};
            float b[4] = {b4.x, b4.y, b4.z, b4.w};
#pragma unroll
            for (int i = 0; i < 4; ++i)
#pragma unroll
                for (int j = 0; j < 4; ++j) acc[i][j] = fmaf(a[i], b[j], acc[i][j]);
        }
        __syncthreads();
    }
#pragma unroll
    for (int i = 0; i < 4; ++i) {
        int m = m0 + ty * 4 + i;
#pragma unroll
        for (int j = 0; j < 4; ++j) {
            int n = n0 + tx * 4 + j;
            C[(size_t)m * 768 + n] = acc[i][j] + bias[n];
        }
    }
}

// ---------------------------------------------------------------------------
__global__ void conv_w2_kernel(const float* __restrict__ W2, ushort* __restrict__ Wb) {
    int row = blockIdx.x;
    int col = threadIdx.x;
    float v = (row < VOCAB_) ? W2[(size_t)row * 256 + col] : 0.f;
    Wb[(size_t)row * 256 + col] = f32_to_bf16_bits(v);
}

// ---------------------------------------------------------------------------
// Fused GRU cell + both attentions. One block per row n.
// keys[b][h][s] = enc_flat[b*25600 + h*100 + s]  (reshape, NOT transpose)
// Scores: 200 active lanes (2 half-K partials), then tree reductions.
// ---------------------------------------------------------------------------
__global__ __launch_bounds__(256) void dec_attn_kernel(
    const float* __restrict__ gi, const float* __restrict__ gh,
    const float* __restrict__ h0, const float* __restrict__ tok_output,
    const float* __restrict__ sbtao, float* __restrict__ cat) {
    __shared__ float decs[256];
    __shared__ float par[2][100];
    __shared__ float sc[100];
    __shared__ float redbuf[128];

    int n = blockIdx.x;
    int b = n / 30;
    int tid = threadIdx.x;

    // GRU cell
    float gir = gi[(size_t)n * 768 + tid];
    float giz = gi[(size_t)n * 768 + 256 + tid];
    float gin = gi[(size_t)n * 768 + 512 + tid];
    float ghr = gh[(size_t)b * 768 + tid];
    float ghz = gh[(size_t)b * 768 + 256 + tid];
    float ghn = gh[(size_t)b * 768 + 512 + tid];
    float r = 1.f / (1.f + expf(-(gir + ghr)));
    float z = 1.f / (1.f + expf(-(giz + ghz)));
    float nnv = tanhf(gin + r * ghn);
    float d = (1.f - z) * nnv + z * h0[(size_t)b * 256 + tid];
    decs[tid] = d;
    cat[(size_t)n * 768 + 256 + tid] = d;
    __syncthreads();

    for (int a = 0; a < 2; ++a) {
        const float* e = (a == 0 ? tok_output : sbtao) + (size_t)b * 25600;
        int colbase = (a == 0) ? 0 : 512;
        // scores: 200 lanes, each sums 128 h's for one s
        if (tid < 200) {
            int half = (tid >= 100) ? 1 : 0;
            int s = tid - half * 100;
            float acc = 0.f;
            for (int h = 0; h < 128; ++h) {
                int hh = half * 128 + h;
                acc = fmaf(decs[hh], e[hh * 100 + s], acc);
            }
            par[half][s] = acc;
        }
        __syncthreads();
        if (tid < 100) sc[tid] = par[0][tid] + par[1][tid];
        __syncthreads();
        // max (tree)
        if (tid < 128) redbuf[tid] = (tid < 100) ? sc[tid] : -1e30f;
        __syncthreads();
        for (int off = 64; off > 0; off >>= 1) {
            if (tid < off) redbuf[tid] = fmaxf(redbuf[tid], redbuf[tid + off]);
            __syncthreads();
        }
        float mx = redbuf[0];
        __syncthreads();
        if (tid < 100) sc[tid] = expf(sc[tid] - mx);
        __syncthreads();
        // sum (tree)
        if (tid < 128) redbuf[tid] = (tid < 100) ? sc[tid] : 0.f;
        __syncthreads();
        for (int off = 64; off > 0; off >>= 1) {
            if (tid < off) redbuf[tid] += redbuf[tid + off];
            __syncthreads();
        }
        float inv = 1.f / redbuf[0];
        __syncthreads();
        // context
        float acc = 0.f;
        for (int s = 0; s < 100; ++s)
            acc = fmaf(sc[s], e[(size_t)s * 256 + tid], acc);
        cat[(size_t)n * 768 + colbase + tid] = acc * inv;
        __syncthreads();
    }
}

// ---------------------------------------------------------------------------
// fp32 vector GEMM (W1): C = relu(A @ B^T + bias), plus fused bf16 copy.
// ---------------------------------------------------------------------------
template <bool RELU>
__global__ __launch_bounds__(256) void gemm_nt_kernel(
    const float* __restrict__ A, const float* __restrict__ Bm,
    const float* __restrict__ bias, float* __restrict__ C,
    ushort* __restrict__ Cbf,
    int M, int N, int K) {
    __shared__ float As[32][68];
    __shared__ float Bs[32][68];

    const int tid = threadIdx.x;
    const int m0 = blockIdx.y * 64;
    const int n0 = blockIdx.x * 64;
    const int tx = tid & 15;
    const int ty = tid >> 4;
    const int lrow = tid >> 3;
    const int lcol = (tid & 7) * 4;

    float acc[4][4];
#pragma unroll
    for (int i = 0; i < 4; ++i)
#pragma unroll
        for (int j = 0; j < 4; ++j) acc[i][j] = 0.f;

    for (int k0 = 0; k0 < K; k0 += 32) {
#pragma unroll
        for (int half = 0; half < 2; ++half) {
            int m = lrow + half * 32;
            float4 av = *reinterpret_cast<const float4*>(
                A + (size_t)(m0 + m) * K + k0 + lcol);
            As[lcol + 0][m] = av.x; As[lcol + 1][m] = av.y;
            As[lcol + 2][m] = av.z; As[lcol + 3][m] = av.w;
            int n = lrow + half * 32;
            float4 bv = make_float4(0.f, 0.f, 0.f, 0.f);
            if (n0 + n < N)
                bv = *reinterpret_cast<const float4*>(
                    Bm + (size_t)(n0 + n) * K + k0 + lcol);
            Bs[lcol + 0][n] = bv.x; Bs[lcol + 1][n] = bv.y;
            Bs[lcol + 2][n] = bv.z; Bs[lcol + 3][n] = bv.w;
        }
        __syncthreads();
#pragma unroll
        for (int k = 0; k < 32; ++k) {
            float4 a4 = *reinterpret_cast<const float4*>(&As[k][ty * 4]);
            float4 b4 = *reinterpret_cast<const float4*>(&Bs[k][tx * 4]);
            float a[4] = {a4.x, a4.y, a4.z, a4.w};
            float b[4] = {b4.x, b4.y, b4.z, b4.w};
#pragma unroll
            for (int i = 0; i < 4; ++i)
#pragma unroll
                for (int j = 0; j < 4; ++j) acc[i][j] = fmaf(a[i], b[j], acc[i][j]);
        }
        __syncthreads();
    }
#pragma unroll
    for (int i = 0; i < 4; ++i) {
        int m = m0 + ty * 4 + i;
#pragma unroll
        for (int j = 0; j < 4; ++j) {
            int n = n0 + tx * 4 + j;
            if (n < N) {
                float v = acc[i][j] + bias[n];
                if (RELU) v = fmaxf(v, 0.f);
                C[(size_t)m * N + n] = v;
                if (Cbf) Cbf[(size_t)m * N + n] = f32_to_bf16_bits(v);
            }
        }
    }
}

// ---------------------------------------------------------------------------
// bf16 MFMA GEMM, two-pass, FULL-K LDS resident (K=256 fits: 64KB + 64KB).
// Stage everything with global_load_lds (1KB per issue), ONE barrier, then
// 128 MFMA per wave with no further syncs. K-slice order kk=0..7 identical
// to the previous BK=64 version -> bit-identical accumulation.
// MODE 0 (stats): per-row partial max/sumexp -> pmax/psum. NO C store.
// MODE 1 (store): identical accumulation; writes logprob = relu(acc+bias) -
// row_lse; appends argmax candidates.
// ---------------------------------------------------------------------------
template <int MODE>
__global__ __launch_bounds__(256) void mfma_gemm_kernel(
    const ushort* __restrict__ Abf, const ushort* __restrict__ Bbf,
    const float* __restrict__ b2, float* __restrict__ C,
    float* __restrict__ pmax, float* __restrict__ psum,
    const float* __restrict__ row_max, const float* __restrict__ row_lse,
    int* __restrict__ cnt, int* __restrict__ cand) {
    __shared__ ushort As[128 * 256];   // 64 KB, full-K A slab
    __shared__ ushort Bs[128 * 256];   // 64 KB, full-K B slab
    __shared__ float pmL[128][2];
    __shared__ float psL[128][2];

    const int tid = threadIdx.x;
    const int m0 = blockIdx.x * 128;
    const int n0 = blockIdx.y * 128;
    const int nblk = blockIdx.y;
    const int wave = tid >> 6, lane = tid & 63;
    const int wm = wave >> 1, wn = wave & 1;
    const int q = lane >> 4, ln = lane & 15;

    // staging: per wave 16 issues each for A and B; issue i covers rows
    // [wave*32 + i*2, +2).  lane l -> row += (l>>5), col elem (l&31)*8.
    // LDS dest = wave-uniform base + lane*16 (linear, matches HW contract).
    const int srow_off = lane >> 5;          // 0..1
    const int sce = (lane & 31) * 8;         // elem col offset

#pragma unroll
    for (int i = 0; i < 16; ++i) {
        int rbase = wave * 32 + i * 2;
        const ushort* ga = Abf + (size_t)(m0 + rbase + srow_off) * 256 + sce;
        const ushort* gb = Bbf + (size_t)(n0 + rbase + srow_off) * 256 + sce;
        __builtin_amdgcn_global_load_lds(
            (const __attribute__((address_space(1))) unsigned int*)ga,
            (__attribute__((address_space(3))) unsigned int*)&As[rbase * 256],
            16, 0, 0);
        __builtin_amdgcn_global_load_lds(
            (const __attribute__((address_space(1))) unsigned int*)gb,
            (__attribute__((address_space(3))) unsigned int*)&Bs[rbase * 256],
            16, 0, 0);
    }
    __syncthreads();   // compiler drains vmcnt(0) before barrier

    floatx4 acc[4][4];
#pragma unroll
    for (int i = 0; i < 4; ++i)
#pragma unroll
        for (int j = 0; j < 4; ++j) acc[i][j] = (floatx4)0.f;

#pragma unroll
    for (int kk = 0; kk < 8; ++kk) {
        short8 af[4], bfr[4];
#pragma unroll
        for (int mt = 0; mt < 4; ++mt)
            af[mt] = *reinterpret_cast<const short8*>(
                &As[(wm * 64 + mt * 16 + ln) * 256 + kk * 32 + q * 8]);
#pragma unroll
        for (int nt = 0; nt < 4; ++nt)
            bfr[nt] = *reinterpret_cast<const short8*>(
                &Bs[(wn * 64 + nt * 16 + ln) * 256 + kk * 32 + q * 8]);
#pragma unroll
        for (int mt = 0; mt < 4; ++mt)
#pragma unroll
            for (int nt = 0; nt < 4; ++nt)
                acc[mt][nt] = __builtin_amdgcn_mfma_f32_16x16x32_bf16(
                    af[mt], bfr[nt], acc[mt][nt], 0, 0, 0);
    }

    // epilogue
    float bias[4]; int nn[4];
#pragma unroll
    for (int nt = 0; nt < 4; ++nt) {
        int n = n0 + wn * 64 + nt * 16 + ln;
        nn[nt] = n;
        bias[nt] = (n < VOCAB_) ? b2[n] : 0.f;
    }

    if (MODE == 0) {
#pragma unroll
        for (int mt = 0; mt < 4; ++mt) {
#pragma unroll
            for (int r = 0; r < 4; ++r) {
                float vv[4]; float lmax = -1e30f;
#pragma unroll
                for (int nt = 0; nt < 4; ++nt) {
                    float v = acc[mt][nt][r] + bias[nt];
                    v = fmaxf(v, 0.f);
                    if (nn[nt] >= VOCAB_) v = -1e30f;
                    vv[nt] = v;
                    lmax = fmaxf(lmax, v);
                }
#pragma unroll
                for (int off = 1; off < 16; off <<= 1)
                    lmax = fmaxf(lmax, __shfl_xor(lmax, off, 64));
                float ls = 0.f;
#pragma unroll
                for (int nt = 0; nt < 4; ++nt) ls += __expf(vv[nt] - lmax);
#pragma unroll
                for (int off = 1; off < 16; off <<= 1)
                    ls += __shfl_xor(ls, off, 64);
                if (ln == 0) {
                    int rl = wm * 64 + mt * 16 + q * 4 + r;
                    pmL[rl][wn] = lmax;
                    psL[rl][wn] = ls;
                }
            }
        }
        __syncthreads();
        if (tid < 128) {
            float m1 = pmL[tid][0], m2 = pmL[tid][1];
            float nm = fmaxf(m1, m2);
            float s = psL[tid][0] * __expf(m1 - nm) + psL[tid][1] * __expf(m2 - nm);
            pmax[(size_t)(m0 + tid) * NBLK + nblk] = nm;
            psum[(size_t)(m0 + tid) * NBLK + nblk] = s;
        }
    } else {
#pragma unroll
        for (int mt = 0; mt < 4; ++mt) {
#pragma unroll
            for (int r = 0; r < 4; ++r) {
                int m = m0 + wm * 64 + mt * 16 + q * 4 + r;
                float thr = row_max[m] - 0.03f;
                float rl = row_lse[m];
#pragma unroll
                for (int nt = 0; nt < 4; ++nt) {
                    if (nn[nt] < VOCAB_) {
                        float v = acc[mt][nt][r] + bias[nt];
                        v = fmaxf(v, 0.f);
                        C[(size_t)m * VOCAB_ + nn[nt]] = v - rl;
                        if (v >= thr) {
                            int k = atomicAdd(&cnt[m], 1);
                            if (k < CAP) cand[m * CAP + k] = nn[nt];
                        }
                    }
                }
            }
        }
    }
}

// ---------------------------------------------------------------------------
// Merge 391 per-block partials per row -> row_max, row_lse; zero cand count
// ---------------------------------------------------------------------------
__global__ __launch_bounds__(128) void reduce_rows_kernel(
    const float* __restrict__ pmax, const float* __restrict__ psum,
    float* __restrict__ row_max, float* __restrict__ row_lse,
    int* __restrict__ cnt) {
    __shared__ float sm[128], ss[128];
    int row = blockIdx.x, tid = threadIdx.x;
    if (tid == 0) cnt[row] = 0;
    const float* pm = pmax + (size_t)row * NBLK;
    const float* ps = psum + (size_t)row * NBLK;
    float m = -1e30f, s = 0.f;
    for (int i = tid; i < NBLK; i += 128) {
        float m2 = pm[i], s2 = ps[i];
        float nm = fmaxf(m, m2);
        s = s * __expf(m - nm) + s2 * __expf(m2 - nm);
        m = nm;
    }
    sm[tid] = m; ss[tid] = s;
    __syncthreads();
    for (int off = 64; off > 0; off >>= 1) {
        if (tid < off) {
            float m2 = sm[tid + off], s2 = ss[tid + off];
            float nm = fmaxf(sm[tid], m2);
            ss[tid] = ss[tid] * __expf(sm[tid] - nm) + s2 * __expf(m2 - nm);
            sm[tid] = nm;
        }
        __syncthreads();
    }
    if (tid == 0) {
        row_max[row] = sm[0];
        row_lse[row] = sm[0] + logf(ss[0]);
    }
}

// ---------------------------------------------------------------------------
// Per row: recompute candidates exactly in fp64, write exact argmax as float.
// ---------------------------------------------------------------------------
__global__ __launch_bounds__(256) void final_cand_kernel(
    const int* __restrict__ cnt, const int* __restrict__ cand,
    const float* __restrict__ out1, const float* __restrict__ W2,
    const float* __restrict__ b2, float* __restrict__ seq) {
    __shared__ float o1s[256];
    __shared__ double red[256];
    __shared__ double bestv_s;
    __shared__ int besti_s;

    int row = blockIdx.x, tid = threadIdx.x;
    if (tid == 0) { bestv_s = -1e300; besti_s = 0x7fffffff; }
    o1s[tid] = out1[(size_t)row * 256 + tid];
    __syncthreads();

    int nc = min(cnt[row], CAP);
    for (int j = 0; j < nc; ++j) {
        int c = cand[row * CAP + j];
        red[tid] = (double)o1s[tid] * (double)W2[(size_t)c * 256 + tid];
        __syncthreads();
        for (int off = 128; off > 0; off >>= 1) {
            if (tid < off) red[tid] += red[tid + off];
            __syncthreads();
        }
        if (tid == 0) {
            double v = red[0] + (double)b2[c];
            if (v < 0.0) v = 0.0;
            if (v > bestv_s || (v == bestv_s && c < besti_s)) { bestv_s = v; besti_s = c; }
        }
        __syncthreads();
    }
    if (tid == 0) seq[row] = (float)(besti_s == 0x7fffffff ? 0 : besti_s);
}

// ---------------------------------------------------------------------------
extern "C" void kernel_launch(void* const* d_in, const int* in_sizes, int n_in,
                              void* d_out, int out_size, void* d_ws, size_t ws_size,
                              hipStream_t stream) {
    const int* comment_input = (const int*)d_in[1];
    const float* tok_output  = (const float*)d_in[2];
    const float* h0          = (const float*)d_in[3];
    const float* sbtao       = (const float*)d_in[4];
    const float* wemb        = (const float*)d_in[5];
    const float* W_ih        = (const float*)d_in[6];
    const float* W_hh        = (const float*)d_in[7];
    const float* b_ih        = (const float*)d_in[8];
    const float* b_hh        = (const float*)d_in[9];
    const float* W1          = (const float*)d_in[10];
    const float* b1          = (const float*)d_in[11];
    const float* W2          = (const float*)d_in[12];
    const float* b2          = (const float*)d_in[13];

    float* out    = (float*)d_out;
    float* seq    = out;
    float* logits = out + NROW;

    float* ws      = (float*)d_ws;
    float* scratch = ws;                    // 491520 floats (cnt/cand)
    float* gi      = scratch + 491520;      // 1474560
    float* gh      = gi + 1474560;          // 49152
    float* cat     = gh + 49152;            // 1474560
    float* out1    = cat + 1474560;         // 491520
    float* pmax    = out1 + 491520;         // 1920*391 = 750720
    float* psum    = pmax + 750720;         // 750720
    float* row_max = psum + 750720;         // 1920
    float* row_lse = row_max + 1920;        // 1920
    ushort* out1b  = (ushort*)(row_lse + 1920);              // 1920*256 bf16 = 245760 float slots
    ushort* W2b    = (ushort*)(row_lse + 1920 + 245760);     // 50048*256 bf16 = 6406144 float slots
    int* cnt       = (int*)scratch;          // 1920 ints
    int* cand      = cnt + 1920;             // 1920*128 ints

    // 1: gh GEMM + gi GEMM (gather fused)
    front_gemm_kernel<<<372, 256, 0, stream>>>(
        h0, W_hh, b_hh, gh, comment_input, wemb, W_ih, b_ih, gi);

    // 2: W2 -> bf16
    conv_w2_kernel<<<NPAD, 256, 0, stream>>>(W2, W2b);

    // 3: GRU cell + both attentions
    dec_attn_kernel<<<NROW, 256, 0, stream>>>(
        gi, gh, h0, tok_output, sbtao, cat);

    // 4: W1 GEMM, also emits bf16 out1b (fused conversion)
    gemm_nt_kernel<true><<<dim3(4, 30), 256, 0, stream>>>(
        cat, W1, b1, out1, out1b, NROW, 256, 768);

    // 5: pass 1, stats only (no logits store)
    mfma_gemm_kernel<0><<<dim3(15, NBLK), 256, 0, stream>>>(
        out1b, W2b, b2, logits, pmax, psum, nullptr, nullptr, nullptr, nullptr);

    // 6
    reduce_rows_kernel<<<NROW, 128, 0, stream>>>(pmax, psum, row_max, row_lse, cnt);

    // 7: pass 2, recompute (bit-identical), write logprobs, collect candidates
    mfma_gemm_kernel<1><<<dim3(15, NBLK), 256, 0, stream>>>(
        out1b, W2b, b2, logits, nullptr, nullptr, row_max, row_lse, cnt, cand);

    // 8
    final_cand_kernel<<<NROW, 256, 0, stream>>>(
        cnt, cand, out1, W2, b2, seq);
}

// Round 9
// 842.500 us; speedup vs baseline: 1.3880x; 1.3880x over previous
//
#include <hip/hip_runtime.h>
#include <hip/hip_bf16.h>
#include <math.h>

#define NROW 1920      // B*T
#define VOCAB_ 50000
#define NPAD 50048     // 391 * 128
#define NBLK 391
#define CAP 128        // max argmax candidates per row

typedef __attribute__((ext_vector_type(8))) short short8;
typedef __attribute__((ext_vector_type(4))) float floatx4;

__device__ inline ushort f32_to_bf16_bits(float f) {
    union { float f; unsigned u; } v; v.f = f;
    unsigned u = v.u;
    u += 0x7fffu + ((u >> 16) & 1u);   // RNE
    return (ushort)(u >> 16);
}

// ---------------------------------------------------------------------------
// Front GEMM: gh (blocks 0..11) and gi (blocks 12..371) in one launch.
//   gh = h0 @ W_hh^T + b_hh            (64 x 768, K=256)
//   gi = wemb[tokens] @ W_ih^T + b_ih  (1920 x 768, K=256, gather fused)
// ---------------------------------------------------------------------------
__global__ __launch_bounds__(256) void front_gemm_kernel(
    const float* __restrict__ h0, const float* __restrict__ W_hh,
    const float* __restrict__ b_hh, float* __restrict__ gh,
    const int* __restrict__ tokens, const float* __restrict__ wemb,
    const float* __restrict__ W_ih, const float* __restrict__ b_ih,
    float* __restrict__ gi) {
    __shared__ float As[32][68];
    __shared__ float Bs[32][68];
    __shared__ int tok_s[64];

    const int tid = threadIdx.x;
    const int bid = blockIdx.x;
    const bool is_gh = (bid < 12);

    int m0, n0;
    const float* Bm;
    const float* bias;
    float* C;
    if (is_gh) {
        m0 = 0; n0 = bid * 64; Bm = W_hh; bias = b_hh; C = gh;
    } else {
        int bb = bid - 12;
        m0 = (bb / 12) * 64; n0 = (bb % 12) * 64;
        Bm = W_ih; bias = b_ih; C = gi;
    }

    if (!is_gh && tid < 64) tok_s[tid] = tokens[m0 + tid];
    __syncthreads();

    const int tx = tid & 15;
    const int ty = tid >> 4;
    const int lrow = tid >> 3;
    const int lcol = (tid & 7) * 4;

    float acc[4][4];
#pragma unroll
    for (int i = 0; i < 4; ++i)
#pragma unroll
        for (int j = 0; j < 4; ++j) acc[i][j] = 0.f;

    for (int k0 = 0; k0 < 256; k0 += 32) {
#pragma unroll
        for (int half = 0; half < 2; ++half) {
            int m = lrow + half * 32;
            const float* arow = is_gh ? (h0 + (size_t)(m0 + m) * 256)
                                      : (wemb + (size_t)tok_s[m] * 256);
            float4 av = *reinterpret_cast<const float4*>(arow + k0 + lcol);
            As[lcol + 0][m] = av.x; As[lcol + 1][m] = av.y;
            As[lcol + 2][m] = av.z; As[lcol + 3][m] = av.w;
            int n = lrow + half * 32;
            float4 bv = *reinterpret_cast<const float4*>(
                Bm + (size_t)(n0 + n) * 256 + k0 + lcol);
            Bs[lcol + 0][n] = bv.x; Bs[lcol + 1][n] = bv.y;
            Bs[lcol + 2][n] = bv.z; Bs[lcol + 3][n] = bv.w;
        }
        __syncthreads();
#pragma unroll
        for (int k = 0; k < 32; ++k) {
            float4 a4 = *reinterpret_cast<const float4*>(&As[k][ty * 4]);
            float4 b4 = *reinterpret_cast<const float4*>(&Bs[k][tx * 4]);
            float a[4] = {a4.x, a4.y, a4.z, a4.w};
            float b[4] = {b4.x, b4.y, b4.z, b4.w};
#pragma unroll
            for (int i = 0; i < 4; ++i)
#pragma unroll
                for (int j = 0; j < 4; ++j) acc[i][j] = fmaf(a[i], b[j], acc[i][j]);
        }
        __syncthreads();
    }
#pragma unroll
    for (int i = 0; i < 4; ++i) {
        int m = m0 + ty * 4 + i;
#pragma unroll
        for (int j = 0; j < 4; ++j) {
            int n = n0 + tx * 4 + j;
            C[(size_t)m * 768 + n] = acc[i][j] + bias[n];
        }
    }
}

// ---------------------------------------------------------------------------
__global__ void conv_w2_kernel(const float* __restrict__ W2, ushort* __restrict__ Wb) {
    int row = blockIdx.x;
    int col = threadIdx.x;
    float v = (row < VOCAB_) ? W2[(size_t)row * 256 + col] : 0.f;
    Wb[(size_t)row * 256 + col] = f32_to_bf16_bits(v);
}

// ---------------------------------------------------------------------------
// Fused GRU cell + both attentions. One block per row n.
// keys[b][h][s] = enc_flat[b*25600 + h*100 + s]  (reshape, NOT transpose)
// Scores: 200 active lanes (2 half-K partials), then tree reductions.
// ---------------------------------------------------------------------------
__global__ __launch_bounds__(256) void dec_attn_kernel(
    const float* __restrict__ gi, const float* __restrict__ gh,
    const float* __restrict__ h0, const float* __restrict__ tok_output,
    const float* __restrict__ sbtao, float* __restrict__ cat) {
    __shared__ float decs[256];
    __shared__ float par[2][100];
    __shared__ float sc[100];
    __shared__ float redbuf[128];

    int n = blockIdx.x;
    int b = n / 30;
    int tid = threadIdx.x;

    // GRU cell
    float gir = gi[(size_t)n * 768 + tid];
    float giz = gi[(size_t)n * 768 + 256 + tid];
    float gin = gi[(size_t)n * 768 + 512 + tid];
    float ghr = gh[(size_t)b * 768 + tid];
    float ghz = gh[(size_t)b * 768 + 256 + tid];
    float ghn = gh[(size_t)b * 768 + 512 + tid];
    float r = 1.f / (1.f + expf(-(gir + ghr)));
    float z = 1.f / (1.f + expf(-(giz + ghz)));
    float nnv = tanhf(gin + r * ghn);
    float d = (1.f - z) * nnv + z * h0[(size_t)b * 256 + tid];
    decs[tid] = d;
    cat[(size_t)n * 768 + 256 + tid] = d;
    __syncthreads();

    for (int a = 0; a < 2; ++a) {
        const float* e = (a == 0 ? tok_output : sbtao) + (size_t)b * 25600;
        int colbase = (a == 0) ? 0 : 512;
        // scores: 200 lanes, each sums 128 h's for one s
        if (tid < 200) {
            int half = (tid >= 100) ? 1 : 0;
            int s = tid - half * 100;
            float acc = 0.f;
            for (int h = 0; h < 128; ++h) {
                int hh = half * 128 + h;
                acc = fmaf(decs[hh], e[hh * 100 + s], acc);
            }
            par[half][s] = acc;
        }
        __syncthreads();
        if (tid < 100) sc[tid] = par[0][tid] + par[1][tid];
        __syncthreads();
        // max (tree)
        if (tid < 128) redbuf[tid] = (tid < 100) ? sc[tid] : -1e30f;
        __syncthreads();
        for (int off = 64; off > 0; off >>= 1) {
            if (tid < off) redbuf[tid] = fmaxf(redbuf[tid], redbuf[tid + off]);
            __syncthreads();
        }
        float mx = redbuf[0];
        __syncthreads();
        if (tid < 100) sc[tid] = expf(sc[tid] - mx);
        __syncthreads();
        // sum (tree)
        if (tid < 128) redbuf[tid] = (tid < 100) ? sc[tid] : 0.f;
        __syncthreads();
        for (int off = 64; off > 0; off >>= 1) {
            if (tid < off) redbuf[tid] += redbuf[tid + off];
            __syncthreads();
        }
        float inv = 1.f / redbuf[0];
        __syncthreads();
        // context
        float acc = 0.f;
        for (int s = 0; s < 100; ++s)
            acc = fmaf(sc[s], e[(size_t)s * 256 + tid], acc);
        cat[(size_t)n * 768 + colbase + tid] = acc * inv;
        __syncthreads();
    }
}

// ---------------------------------------------------------------------------
// fp32 vector GEMM (W1): C = relu(A @ B^T + bias), plus fused bf16 copy.
// ---------------------------------------------------------------------------
template <bool RELU>
__global__ __launch_bounds__(256) void gemm_nt_kernel(
    const float* __restrict__ A, const float* __restrict__ Bm,
    const float* __restrict__ bias, float* __restrict__ C,
    ushort* __restrict__ Cbf,
    int M, int N, int K) {
    __shared__ float As[32][68];
    __shared__ float Bs[32][68];

    const int tid = threadIdx.x;
    const int m0 = blockIdx.y * 64;
    const int n0 = blockIdx.x * 64;
    const int tx = tid & 15;
    const int ty = tid >> 4;
    const int lrow = tid >> 3;
    const int lcol = (tid & 7) * 4;

    float acc[4][4];
#pragma unroll
    for (int i = 0; i < 4; ++i)
#pragma unroll
        for (int j = 0; j < 4; ++j) acc[i][j] = 0.f;

    for (int k0 = 0; k0 < K; k0 += 32) {
#pragma unroll
        for (int half = 0; half < 2; ++half) {
            int m = lrow + half * 32;
            float4 av = *reinterpret_cast<const float4*>(
                A + (size_t)(m0 + m) * K + k0 + lcol);
            As[lcol + 0][m] = av.x; As[lcol + 1][m] = av.y;
            As[lcol + 2][m] = av.z; As[lcol + 3][m] = av.w;
            int n = lrow + half * 32;
            float4 bv = make_float4(0.f, 0.f, 0.f, 0.f);
            if (n0 + n < N)
                bv = *reinterpret_cast<const float4*>(
                    Bm + (size_t)(n0 + n) * K + k0 + lcol);
            Bs[lcol + 0][n] = bv.x; Bs[lcol + 1][n] = bv.y;
            Bs[lcol + 2][n] = bv.z; Bs[lcol + 3][n] = bv.w;
        }
        __syncthreads();
#pragma unroll
        for (int k = 0; k < 32; ++k) {
            float4 a4 = *reinterpret_cast<const float4*>(&As[k][ty * 4]);
            float4 b4 = *reinterpret_cast<const float4*>(&Bs[k][tx * 4]);
            float a[4] = {a4.x, a4.y, a4.z, a4.w};
            float b[4] = {b4.x, b4.y, b4.z, b4.w};
#pragma unroll
            for (int i = 0; i < 4; ++i)
#pragma unroll
                for (int j = 0; j < 4; ++j) acc[i][j] = fmaf(a[i], b[j], acc[i][j]);
        }
        __syncthreads();
    }
#pragma unroll
    for (int i = 0; i < 4; ++i) {
        int m = m0 + ty * 4 + i;
#pragma unroll
        for (int j = 0; j < 4; ++j) {
            int n = n0 + tx * 4 + j;
            if (n < N) {
                float v = acc[i][j] + bias[n];
                if (RELU) v = fmaxf(v, 0.f);
                C[(size_t)m * N + n] = v;
                if (Cbf) Cbf[(size_t)m * N + n] = f32_to_bf16_bits(v);
            }
        }
    }
}

// ---------------------------------------------------------------------------
// bf16 MFMA GEMM, two-pass, BK=64 global_load_lds staging (m97 pattern).
// REVERTED from full-K single-barrier (R8: 1 block/CU, 4.2e7 bank conflicts,
// MfmaUtil 5.7% -> 346us/pass). This BK=64 form runs ~3 blocks/CU.
// MODE 0 (stats): per-row partial max/sumexp -> pmax/psum. NO C store.
// MODE 1 (store): identical accumulation (bit-identical acc); writes
// logprob = relu(acc+bias) - row_lse; appends argmax candidates.
// ---------------------------------------------------------------------------
template <int MODE>
__global__ __launch_bounds__(256) void mfma_gemm_kernel(
    const ushort* __restrict__ Abf, const ushort* __restrict__ Bbf,
    const float* __restrict__ b2, float* __restrict__ C,
    float* __restrict__ pmax, float* __restrict__ psum,
    const float* __restrict__ row_max, const float* __restrict__ row_lse,
    int* __restrict__ cnt, int* __restrict__ cand) {
    __shared__ ushort As[128 * 64];
    __shared__ ushort Bs[128 * 64];
    __shared__ float pmL[128][2];
    __shared__ float psL[128][2];

    const int tid = threadIdx.x;
    const int m0 = blockIdx.x * 128;
    const int n0 = blockIdx.y * 128;
    const int nblk = blockIdx.y;
    const int wave = tid >> 6, lane = tid & 63;
    const int wm = wave >> 1, wn = wave & 1;
    const int q = lane >> 4, ln = lane & 15;

    const int lrow = lane >> 3;        // 0..7
    const int lcol8 = (lane & 7) * 8;  // elem offset within 64-wide K-step

    floatx4 acc[4][4];
#pragma unroll
    for (int i = 0; i < 4; ++i)
#pragma unroll
        for (int j = 0; j < 4; ++j) acc[i][j] = (floatx4)0.f;

    for (int k0 = 0; k0 < 256; k0 += 64) {
        __syncthreads();   // prior tile's reads complete before overwrite
#pragma unroll
        for (int c = 0; c < 4; ++c) {
            int rbase = wave * 32 + c * 8;
            const ushort* ga = Abf + (size_t)(m0 + rbase + lrow) * 256 + k0 + lcol8;
            const ushort* gb = Bbf + (size_t)(n0 + rbase + lrow) * 256 + k0 + lcol8;
            __builtin_amdgcn_global_load_lds(
                (const __attribute__((address_space(1))) unsigned int*)ga,
                (__attribute__((address_space(3))) unsigned int*)&As[rbase * 64],
                16, 0, 0);
            __builtin_amdgcn_global_load_lds(
                (const __attribute__((address_space(1))) unsigned int*)gb,
                (__attribute__((address_space(3))) unsigned int*)&Bs[rbase * 64],
                16, 0, 0);
        }
        __syncthreads();   // vmcnt(0) drained by compiler before barrier
#pragma unroll
        for (int ks = 0; ks < 2; ++ks) {
            short8 af[4], bf[4];
#pragma unroll
            for (int mt = 0; mt < 4; ++mt)
                af[mt] = *reinterpret_cast<const short8*>(
                    &As[(wm * 64 + mt * 16 + ln) * 64 + ks * 32 + q * 8]);
#pragma unroll
            for (int nt = 0; nt < 4; ++nt)
                bf[nt] = *reinterpret_cast<const short8*>(
                    &Bs[(wn * 64 + nt * 16 + ln) * 64 + ks * 32 + q * 8]);
#pragma unroll
            for (int mt = 0; mt < 4; ++mt)
#pragma unroll
                for (int nt = 0; nt < 4; ++nt)
                    acc[mt][nt] = __builtin_amdgcn_mfma_f32_16x16x32_bf16(
                        af[mt], bf[nt], acc[mt][nt], 0, 0, 0);
        }
    }

    // epilogue
    float bias[4]; int nn[4];
#pragma unroll
    for (int nt = 0; nt < 4; ++nt) {
        int n = n0 + wn * 64 + nt * 16 + ln;
        nn[nt] = n;
        bias[nt] = (n < VOCAB_) ? b2[n] : 0.f;
    }

    if (MODE == 0) {
#pragma unroll
        for (int mt = 0; mt < 4; ++mt) {
#pragma unroll
            for (int r = 0; r < 4; ++r) {
                float vv[4]; float lmax = -1e30f;
#pragma unroll
                for (int nt = 0; nt < 4; ++nt) {
                    float v = acc[mt][nt][r] + bias[nt];
                    v = fmaxf(v, 0.f);
                    if (nn[nt] >= VOCAB_) v = -1e30f;
                    vv[nt] = v;
                    lmax = fmaxf(lmax, v);
                }
#pragma unroll
                for (int off = 1; off < 16; off <<= 1)
                    lmax = fmaxf(lmax, __shfl_xor(lmax, off, 64));
                float ls = 0.f;
#pragma unroll
                for (int nt = 0; nt < 4; ++nt) ls += __expf(vv[nt] - lmax);
#pragma unroll
                for (int off = 1; off < 16; off <<= 1)
                    ls += __shfl_xor(ls, off, 64);
                if (ln == 0) {
                    int rl = wm * 64 + mt * 16 + q * 4 + r;
                    pmL[rl][wn] = lmax;
                    psL[rl][wn] = ls;
                }
            }
        }
        __syncthreads();
        if (tid < 128) {
            float m1 = pmL[tid][0], m2 = pmL[tid][1];
            float nm = fmaxf(m1, m2);
            float s = psL[tid][0] * __expf(m1 - nm) + psL[tid][1] * __expf(m2 - nm);
            pmax[(size_t)(m0 + tid) * NBLK + nblk] = nm;
            psum[(size_t)(m0 + tid) * NBLK + nblk] = s;
        }
    } else {
#pragma unroll
        for (int mt = 0; mt < 4; ++mt) {
#pragma unroll
            for (int r = 0; r < 4; ++r) {
                int m = m0 + wm * 64 + mt * 16 + q * 4 + r;
                float thr = row_max[m] - 0.03f;
                float rl = row_lse[m];
#pragma unroll
                for (int nt = 0; nt < 4; ++nt) {
                    if (nn[nt] < VOCAB_) {
                        float v = acc[mt][nt][r] + bias[nt];
                        v = fmaxf(v, 0.f);
                        C[(size_t)m * VOCAB_ + nn[nt]] = v - rl;
                        if (v >= thr) {
                            int k = atomicAdd(&cnt[m], 1);
                            if (k < CAP) cand[m * CAP + k] = nn[nt];
                        }
                    }
                }
            }
        }
    }
}

// ---------------------------------------------------------------------------
// Merge 391 per-block partials per row -> row_max, row_lse; zero cand count
// ---------------------------------------------------------------------------
__global__ __launch_bounds__(128) void reduce_rows_kernel(
    const float* __restrict__ pmax, const float* __restrict__ psum,
    float* __restrict__ row_max, float* __restrict__ row_lse,
    int* __restrict__ cnt) {
    __shared__ float sm[128], ss[128];
    int row = blockIdx.x, tid = threadIdx.x;
    if (tid == 0) cnt[row] = 0;
    const float* pm = pmax + (size_t)row * NBLK;
    const float* ps = psum + (size_t)row * NBLK;
    float m = -1e30f, s = 0.f;
    for (int i = tid; i < NBLK; i += 128) {
        float m2 = pm[i], s2 = ps[i];
        float nm = fmaxf(m, m2);
        s = s * __expf(m - nm) + s2 * __expf(m2 - nm);
        m = nm;
    }
    sm[tid] = m; ss[tid] = s;
    __syncthreads();
    for (int off = 64; off > 0; off >>= 1) {
        if (tid < off) {
            float m2 = sm[tid + off], s2 = ss[tid + off];
            float nm = fmaxf(sm[tid], m2);
            ss[tid] = ss[tid] * __expf(sm[tid] - nm) + s2 * __expf(m2 - nm);
            sm[tid] = nm;
        }
        __syncthreads();
    }
    if (tid == 0) {
        row_max[row] = sm[0];
        row_lse[row] = sm[0] + logf(ss[0]);
    }
}

// ---------------------------------------------------------------------------
// Per row: recompute candidates exactly in fp64, write exact argmax as float.
// ---------------------------------------------------------------------------
__global__ __launch_bounds__(256) void final_cand_kernel(
    const int* __restrict__ cnt, const int* __restrict__ cand,
    const float* __restrict__ out1, const float* __restrict__ W2,
    const float* __restrict__ b2, float* __restrict__ seq) {
    __shared__ float o1s[256];
    __shared__ double red[256];
    __shared__ double bestv_s;
    __shared__ int besti_s;

    int row = blockIdx.x, tid = threadIdx.x;
    if (tid == 0) { bestv_s = -1e300; besti_s = 0x7fffffff; }
    o1s[tid] = out1[(size_t)row * 256 + tid];
    __syncthreads();

    int nc = min(cnt[row], CAP);
    for (int j = 0; j < nc; ++j) {
        int c = cand[row * CAP + j];
        red[tid] = (double)o1s[tid] * (double)W2[(size_t)c * 256 + tid];
        __syncthreads();
        for (int off = 128; off > 0; off >>= 1) {
            if (tid < off) red[tid] += red[tid + off];
            __syncthreads();
        }
        if (tid == 0) {
            double v = red[0] + (double)b2[c];
            if (v < 0.0) v = 0.0;
            if (v > bestv_s || (v == bestv_s && c < besti_s)) { bestv_s = v; besti_s = c; }
        }
        __syncthreads();
    }
    if (tid == 0) seq[row] = (float)(besti_s == 0x7fffffff ? 0 : besti_s);
}

// ---------------------------------------------------------------------------
extern "C" void kernel_launch(void* const* d_in, const int* in_sizes, int n_in,
                              void* d_out, int out_size, void* d_ws, size_t ws_size,
                              hipStream_t stream) {
    const int* comment_input = (const int*)d_in[1];
    const float* tok_output  = (const float*)d_in[2];
    const float* h0          = (const float*)d_in[3];
    const float* sbtao       = (const float*)d_in[4];
    const float* wemb        = (const float*)d_in[5];
    const float* W_ih        = (const float*)d_in[6];
    const float* W_hh        = (const float*)d_in[7];
    const float* b_ih        = (const float*)d_in[8];
    const float* b_hh        = (const float*)d_in[9];
    const float* W1          = (const float*)d_in[10];
    const float* b1          = (const float*)d_in[11];
    const float* W2          = (const float*)d_in[12];
    const float* b2          = (const float*)d_in[13];

    float* out    = (float*)d_out;
    float* seq    = out;
    float* logits = out + NROW;

    float* ws      = (float*)d_ws;
    float* scratch = ws;                    // 491520 floats (cnt/cand)
    float* gi      = scratch + 491520;      // 1474560
    float* gh      = gi + 1474560;          // 49152
    float* cat     = gh + 49152;            // 1474560
    float* out1    = cat + 1474560;         // 491520
    float* pmax    = out1 + 491520;         // 1920*391 = 750720
    float* psum    = pmax + 750720;         // 750720
    float* row_max = psum + 750720;         // 1920
    float* row_lse = row_max + 1920;        // 1920
    ushort* out1b  = (ushort*)(row_lse + 1920);              // 1920*256 bf16 = 245760 float slots
    ushort* W2b    = (ushort*)(row_lse + 1920 + 245760);     // 50048*256 bf16 = 6406144 float slots
    int* cnt       = (int*)scratch;          // 1920 ints
    int* cand      = cnt + 1920;             // 1920*128 ints

    // 1: gh GEMM + gi GEMM (gather fused)
    front_gemm_kernel<<<372, 256, 0, stream>>>(
        h0, W_hh, b_hh, gh, comment_input, wemb, W_ih, b_ih, gi);

    // 2: W2 -> bf16
    conv_w2_kernel<<<NPAD, 256, 0, stream>>>(W2, W2b);

    // 3: GRU cell + both attentions
    dec_attn_kernel<<<NROW, 256, 0, stream>>>(
        gi, gh, h0, tok_output, sbtao, cat);

    // 4: W1 GEMM, also emits bf16 out1b (fused conversion)
    gemm_nt_kernel<true><<<dim3(4, 30), 256, 0, stream>>>(
        cat, W1, b1, out1, out1b, NROW, 256, 768);

    // 5: pass 1, stats only (no logits store)
    mfma_gemm_kernel<0><<<dim3(15, NBLK), 256, 0, stream>>>(
        out1b, W2b, b2, logits, pmax, psum, nullptr, nullptr, nullptr, nullptr);

    // 6
    reduce_rows_kernel<<<NROW, 128, 0, stream>>>(pmax, psum, row_max, row_lse, cnt);

    // 7: pass 2, recompute (bit-identical), write logprobs, collect candidates
    mfma_gemm_kernel<1><<<dim3(15, NBLK), 256, 0, stream>>>(
        out1b, W2b, b2, logits, nullptr, nullptr, row_max, row_lse, cnt, cand);

    // 8
    final_cand_kernel<<<NROW, 256, 0, stream>>>(
        cnt, cand, out1, W2, b2, seq);
}